// Round 1
// baseline (221.537 us; speedup 1.0000x reference)
//
#include <hip/hip_runtime.h>
#include <cstdint>
#include <cstddef>

// Problem dims
// B=8, C=256, N=1024, T=60
// seq [B][C][N][T] fp32, out [B][T][T] fp32
//
// ws layout (float offsets):
//   f1p   : 4 c-group partials of [B][T][N]  -> 4*8*60*1024 = 1,966,080
//   f2p   : [B][C][64 n-chunks][T]           -> 8*256*64*60 = 7,864,320  @ 1,966,080
//   f2    : [B][C][T]                        -> 122,880               @ 9,830,400
//   g1    : [B][T][C]                        -> 122,880               @ 9,953,280
//   logits: [B][T][T]                        -> 28,800                @ 10,076,160
//   l2    : [B][T][T]                        -> 28,800                @ 10,104,960
//   stats : mean[60] @ +0, rstd[60] @ +64    -> 128                   @ 10,133,760
// total 10,133,888 floats = ~40.5 MB

// ---------------------------------------------------------------------------
// Kernel A: single pass over seq producing f1 partials (register-accumulated
// over the block's 64 c's) and f2 partials (LDS-reduced over the block's 16 n's).
// grid 2048 = b(8) x cg(4) x nc(64); block 256 (240 active).
// Thread: r = tid%15 -> t-quad t0=4r ; q = tid/15 -> n = nc*16 + q.
// float4 element offset within a c-plane chunk: 4*tid = 60*q + 4*r. Coalesced.
// ---------------------------------------------------------------------------
__global__ __launch_bounds__(256) void kA(const float* __restrict__ seq,
                                          const float* __restrict__ w1,
                                          const float* __restrict__ w2,
                                          float* __restrict__ f1p,
                                          float* __restrict__ f2p) {
    const int blk = blockIdx.x;          // 2048
    const int b   = blk >> 8;            // 0..7
    const int cg  = (blk >> 6) & 3;      // 0..3
    const int nc  = blk & 63;            // 0..63
    const int n0  = nc << 4;             // n chunk base
    const int tid = threadIdx.x;
    const bool act = (tid < 240);
    const int r  = tid % 15;
    const int q  = tid / 15;
    const int t0 = r << 2;
    const int n  = n0 + q;

    __shared__ float red[960];

    float w2n = 0.f;
    if (act) w2n = w2[n];

    const int c0 = cg << 6;
    const float* p = seq + (((size_t)(b * 256 + c0) * 1024 + (size_t)n0) * 60) + 4 * tid;
    const size_t cstride = (size_t)1024 * 60;

    float4 acc = make_float4(0.f, 0.f, 0.f, 0.f);
    float4 v0 = make_float4(0.f, 0.f, 0.f, 0.f);
    float4 v1 = v0;
    if (act) v0 = *(const float4*)p;
    p += cstride;
    if (act) v1 = *(const float4*)p;
    p += cstride;

    for (int i = 0; i < 64; ++i) {
        float4 cur = v0;
        v0 = v1;
        if (i < 62) {                 // uniform branch: prefetch c0+i+2
            if (act) v1 = *(const float4*)p;
            p += cstride;
        }
        const float wc = w1[c0 + i];
        acc.x += wc * cur.x;
        acc.y += wc * cur.y;
        acc.z += wc * cur.z;
        acc.w += wc * cur.w;

        if (act) {
            float4 f2v = make_float4(w2n * cur.x, w2n * cur.y, w2n * cur.z, w2n * cur.w);
            *(float4*)(&red[4 * tid]) = f2v;   // red[60*q + t]
        }
        __syncthreads();
        if (tid < 60) {
            float s = 0.f;
            #pragma unroll
            for (int q2 = 0; q2 < 16; ++q2) s += red[q2 * 60 + tid];
            f2p[(((size_t)(b * 256 + c0 + i) * 64) + (size_t)nc) * 60 + tid] = s;
        }
        __syncthreads();
    }

    if (act) {
        float* dst = f1p + (((size_t)(cg * 8 + b) * 60 + (size_t)t0) * 1024) + n;
        dst[0]    = acc.x;
        dst[1024] = acc.y;
        dst[2048] = acc.z;
        dst[3072] = acc.w;
    }
}

// ---------------------------------------------------------------------------
// Kernel B: reduce f2 partials over 64 n-chunks. grid 2048 = b*256+c, block 64.
// ---------------------------------------------------------------------------
__global__ __launch_bounds__(64) void kB(const float* __restrict__ f2p,
                                         float* __restrict__ f2) {
    const int bc = blockIdx.x;
    const int t  = threadIdx.x;
    if (t >= 60) return;
    const float* src = f2p + (size_t)bc * 64 * 60 + t;
    float s = 0.f;
    #pragma unroll 8
    for (int nc = 0; nc < 64; ++nc) s += src[nc * 60];
    f2[(size_t)bc * 60 + t] = s;
}

// ---------------------------------------------------------------------------
// Kernel C: g1[b,t,c] = sum_n f1[b,t,n] * w[n,c], with f1 = sum of 4 partials.
// grid 120 = b(8) x tg(15) (4 t-rows per block); block 256 (thread = c).
// f1 rows staged in LDS (broadcast reads); w reads coalesced across threads.
// ---------------------------------------------------------------------------
__global__ __launch_bounds__(256) void kC(const float* __restrict__ f1p,
                                          const float* __restrict__ w,
                                          float* __restrict__ g1) {
    const int b  = blockIdx.x / 15;
    const int tg = blockIdx.x % 15;
    const int tid = threadIdx.x;
    __shared__ float fl[4 * 1024];

    for (int idx = tid; idx < 1024; idx += 256) {   // 1024 float4 = 4096 floats
        const int row  = idx >> 8;                  // 0..3
        const int col4 = idx & 255;                 // float4 index in row
        float4 sum = make_float4(0.f, 0.f, 0.f, 0.f);
        #pragma unroll
        for (int g = 0; g < 4; ++g) {
            const float4 vp = *(const float4*)(f1p +
                (((size_t)(g * 8 + b) * 60 + (size_t)(tg * 4 + row)) * 1024) + 4 * col4);
            sum.x += vp.x; sum.y += vp.y; sum.z += vp.z; sum.w += vp.w;
        }
        *(float4*)(&fl[row * 1024 + 4 * col4]) = sum;
    }
    __syncthreads();

    float a0 = 0.f, a1 = 0.f, a2 = 0.f, a3 = 0.f;
    for (int nn = 0; nn < 1024; ++nn) {
        const float wv = w[nn * 256 + tid];
        a0 += fl[nn]          * wv;
        a1 += fl[1024 + nn]   * wv;
        a2 += fl[2048 + nn]   * wv;
        a3 += fl[3072 + nn]   * wv;
    }
    float* dst = g1 + ((size_t)b * 60 + (size_t)(tg * 4)) * 256 + tid;
    dst[0]   = a0;
    dst[256] = a1;
    dst[512] = a2;
    dst[768] = a3;
}

// ---------------------------------------------------------------------------
// Kernel D: logits[b,t,s] = sigmoid( sum_c g1[b,t,c]*f2[b,c,s] + bmat[t,s] )
// grid 480 = b*60+t ; block 64 (thread = s, 60 active).
// ---------------------------------------------------------------------------
__global__ __launch_bounds__(64) void kD(const float* __restrict__ g1,
                                         const float* __restrict__ f2,
                                         const float* __restrict__ bmat,
                                         float* __restrict__ logits) {
    const int bt = blockIdx.x;
    const int b  = bt / 60;
    const int t  = bt % 60;
    const int s  = threadIdx.x;
    const int sc = (s < 60) ? s : 0;
    const float* g = g1 + (size_t)bt * 256;
    const float* f = f2 + (size_t)b * 256 * 60;
    float acc = 0.f;
    for (int c = 0; c < 256; ++c) acc += g[c] * f[c * 60 + sc];
    if (s < 60) {
        const float x = acc + bmat[t * 60 + s];
        logits[(size_t)bt * 60 + s] = 1.f / (1.f + __expf(-x));
    }
}

// ---------------------------------------------------------------------------
// Kernel E: l2[b,i,t] = sum_j v[i,j] * logits[b,j,t]. grid 480, block 64.
// ---------------------------------------------------------------------------
__global__ __launch_bounds__(64) void kE(const float* __restrict__ v,
                                         const float* __restrict__ logits,
                                         float* __restrict__ l2) {
    const int bi = blockIdx.x;
    const int b  = bi / 60;
    const int i  = bi % 60;
    const int t  = threadIdx.x;
    const int tc = (t < 60) ? t : 0;
    const float* lb = logits + (size_t)b * 3600;
    float acc = 0.f;
    for (int j = 0; j < 60; ++j) acc += v[i * 60 + j] * lb[j * 60 + tc];
    if (t < 60) l2[(size_t)bi * 60 + t] = acc;
}

// ---------------------------------------------------------------------------
// Kernel F: BN stats per channel t over all (b,i): mean + rsqrt(var+eps).
// Single block of 64.
// ---------------------------------------------------------------------------
__global__ __launch_bounds__(64) void kF(const float* __restrict__ l2,
                                         float* __restrict__ stats) {
    const int t = threadIdx.x;
    if (t >= 60) return;
    float s = 0.f, ss = 0.f;
    for (int k = 0; k < 480; ++k) {
        const float x = l2[(size_t)k * 60 + t];
        s  += x;
        ss += x * x;
    }
    const float m   = s * (1.f / 480.f);
    const float var = ss * (1.f / 480.f) - m * m;
    stats[t]      = m;
    stats[64 + t] = rsqrtf(var + 1e-5f);
}

// ---------------------------------------------------------------------------
// Kernel G: BN apply + window mask + softmax over last dim. grid 480, block 64
// (one wave; shfl reductions over 64 lanes).
// ---------------------------------------------------------------------------
__global__ __launch_bounds__(64) void kG(const float* __restrict__ l2,
                                         const float* __restrict__ stats,
                                         const float* __restrict__ gamma,
                                         const float* __restrict__ beta,
                                         float* __restrict__ out) {
    const int bi = blockIdx.x;
    const int i  = bi % 60;
    const int t  = threadIdx.x;

    float x = -3.0e38f;
    if (t < 60) {
        const float val = l2[(size_t)bi * 60 + t];
        const float y   = (val - stats[t]) * stats[64 + t] * gamma[t] + beta[t];
        const int  br   = (i < 36) ? (i / 12) : 3;
        const int  lo   = (br < 3) ? br * 12 : 36;
        const int  hi   = (br < 3) ? lo + 12 : 60;
        const bool valid = (t >= lo) && (t < hi);
        x = valid ? y : (y - 1e13f);    // matches ref: logits + (-1e13)*(1-A)
    }
    float mx = x;
    #pragma unroll
    for (int o = 32; o > 0; o >>= 1) mx = fmaxf(mx, __shfl_xor(mx, o));
    float e = 0.f;
    if (t < 60) e = __expf(x - mx);     // masked -> exp(-1e13) -> 0, like ref
    float sm = e;
    #pragma unroll
    for (int o = 32; o > 0; o >>= 1) sm += __shfl_xor(sm, o);
    if (t < 60) out[(size_t)bi * 60 + t] = e / sm;
}

// ---------------------------------------------------------------------------
extern "C" void kernel_launch(void* const* d_in, const int* in_sizes, int n_in,
                              void* d_out, int out_size, void* d_ws, size_t ws_size,
                              hipStream_t stream) {
    const float* seq   = (const float*)d_in[0];
    const float* w1    = (const float*)d_in[1];
    const float* w2    = (const float*)d_in[2];
    const float* w     = (const float*)d_in[3];
    const float* bmat  = (const float*)d_in[4];
    const float* v     = (const float*)d_in[5];
    const float* gamma = (const float*)d_in[6];
    const float* beta  = (const float*)d_in[7];
    float* out = (float*)d_out;
    float* ws  = (float*)d_ws;

    float* f1p    = ws;                 // 1,966,080
    float* f2p    = ws + 1966080;       // 7,864,320
    float* f2     = ws + 9830400;       //   122,880
    float* g1     = ws + 9953280;       //   122,880
    float* logits = ws + 10076160;      //    28,800
    float* l2     = ws + 10104960;      //    28,800
    float* stats  = ws + 10133760;      //       128

    kA<<<2048, 256, 0, stream>>>(seq, w1, w2, f1p, f2p);
    kB<<<2048, 64, 0, stream>>>(f2p, f2);
    kC<<<120, 256, 0, stream>>>(f1p, w, g1);
    kD<<<480, 64, 0, stream>>>(g1, f2, bmat, logits);
    kE<<<480, 64, 0, stream>>>(v, logits, l2);
    kF<<<1, 64, 0, stream>>>(l2, stats);
    kG<<<480, 64, 0, stream>>>(l2, stats, gamma, beta, out);
}